// Round 3
// baseline (123.908 us; speedup 1.0000x reference)
//
#include <hip/hip_runtime.h>

#define N_ 4096
#define K_ 64
#define E_ (N_*K_)
#define H_ 256
#define EPS_ 1e-5f

// tanh(x) = 1 - 2/(exp(2x)+1): no overflow/NaN at |x|->inf, v_exp + v_rcp based
__device__ __forceinline__ float ftanh(float x) {
    float e = __expf(2.0f * x);
    return 1.0f - 2.0f * __builtin_amdgcn_rcpf(e + 1.0f);
}

// W01 = W0 @ W1 (4x256), b01 = b0 @ W1 (+ b1 from block 0). 32 blocks x 8 h-rows.
// W01/b01 region must be pre-zeroed (ws memset).
__global__ __launch_bounds__(256) void prep_kernel(
    const float* __restrict__ W0, const float* __restrict__ b0,
    const float* __restrict__ W1, const float* __restrict__ b1,
    float* __restrict__ W01, float* __restrict__ b01)
{
    int c = threadIdx.x;
    int h0 = blockIdx.x * 8;
    float a0 = 0.f, a1 = 0.f, a2 = 0.f, a3 = 0.f, ab = 0.f;
    #pragma unroll
    for (int h = h0; h < h0 + 8; ++h) {
        float w = W1[h * H_ + c];
        a0 = fmaf(W0[0 * H_ + h], w, a0);
        a1 = fmaf(W0[1 * H_ + h], w, a1);
        a2 = fmaf(W0[2 * H_ + h], w, a2);
        a3 = fmaf(W0[3 * H_ + h], w, a3);
        ab = fmaf(b0[h], w, ab);
    }
    if (blockIdx.x == 0) ab += b1[c];
    atomicAdd(&W01[c], a0);
    atomicAdd(&W01[H_ + c], a1);
    atomicAdd(&W01[2 * H_ + c], a2);
    atomicAdd(&W01[3 * H_ + c], a3);
    atomicAdd(&b01[c], ab);
}

// per-column sum/sumsq of h = tanh(T @ W01 + b01), 128-edge tiles, 2048 blocks
__global__ __launch_bounds__(256, 8) void stats_kernel(
    const float* __restrict__ coor, const float* __restrict__ W01,
    const float* __restrict__ b01, float* __restrict__ sums)
{
    const int c = threadIdx.x;
    const float w0 = W01[c], w1 = W01[H_ + c], w2 = W01[2 * H_ + c], w3 = W01[3 * H_ + c];
    const float bb = b01[c];
    __shared__ float4 T[128];
    const int e0 = blockIdx.x * 128;
    if (c < 128) {
        float4 v = reinterpret_cast<const float4*>(coor)[e0 + c];
        T[c] = make_float4(ftanh(v.x), ftanh(v.y), ftanh(v.z), ftanh(v.w));
    }
    __syncthreads();
    float s = 0.f, s2 = 0.f;
    #pragma unroll 8
    for (int r = 0; r < 128; ++r) {
        float4 t = T[r];
        float h = ftanh(fmaf(t.w, w3, fmaf(t.z, w2,
                        fmaf(t.y, w1, fmaf(t.x, w0, bb)))));
        s += h;
        s2 = fmaf(h, h, s2);
    }
    atomicAdd(&sums[c], s);
    atomicAdd(&sums[H_ + c], s2);
}

// fold BN+weights into per-column 8-float record {w0,w1,w2,w3,b01,a,bf,W2c}
__global__ __launch_bounds__(256) void finalize_kernel(
    const float* __restrict__ sums, const float* __restrict__ gamma,
    const float* __restrict__ beta, const float* __restrict__ W2,
    const float* __restrict__ W01, const float* __restrict__ b01,
    float* __restrict__ folded)
{
    int c = threadIdx.x;
    const float inv = 1.0f / (float)E_;
    float mu = sums[c] * inv;
    float var = fmaf(-mu, mu, sums[H_ + c] * inv);
    float rstd = rsqrtf(var + EPS_);
    float a = gamma[c] * rstd;
    float bf = fmaf(-mu, a, beta[c]);
    folded[c * 8 + 0] = W01[c];
    folded[c * 8 + 1] = W01[H_ + c];
    folded[c * 8 + 2] = W01[2 * H_ + c];
    folded[c * 8 + 3] = W01[3 * H_ + c];
    folded[c * 8 + 4] = b01[c];
    folded[c * 8 + 5] = a;
    folded[c * 8 + 6] = bf;
    folded[c * 8 + 7] = W2[c];
}

// Fused edge kernel: one wave = one row (64 edges). Weights staged in LDS;
// launch_bounds(256,4) frees VGPRs (grid caps us at 4 waves/SIMD anyway) so
// unrolled ds_reads pipeline ahead of the tanh chain.
__global__ __launch_bounds__(256, 4) void edge_kernel(
    const float* __restrict__ coor, const int* __restrict__ idx,
    const float* __restrict__ folded,
    const float* __restrict__ Wq, const float* __restrict__ bq,
    const float* __restrict__ Wk, const float* __restrict__ bk,
    const float* __restrict__ b2,
    const float* __restrict__ geo, const float* __restrict__ ang,
    float* __restrict__ out)
{
    __shared__ float4 FS[2 * H_];  // 8 KB: folded table
    {
        int t = threadIdx.x;
        const float4* F = reinterpret_cast<const float4*>(folded);
        FS[t] = F[t];
        FS[t + 256] = F[t + 256];
    }

    const int lane = threadIdx.x & 63;
    const int row  = blockIdx.x * 4 + (threadIdx.x >> 6);
    const int e    = row * K_ + lane;
    const int col  = idx[E_ + e];

    float4 ce = reinterpret_cast<const float4*>(coor)[e];
    float ex = ce.x + ce.z, ey = ce.y + ce.w;
    // q comes from the row-center element = lane 0 of this wave
    float sx = __shfl(ex, 0), sy = __shfl(ey, 0);
    float att = 0.f;
    #pragma unroll
    for (int j = 0; j < 8; ++j) {
        float qj = fmaf(sy, Wq[8 + j], fmaf(sx, Wq[j], bq[j]));
        float kj = fmaf(ey, Wk[8 + j], fmaf(ex, Wk[j], bk[j]));
        att = fmaf(qj, kj, att);
    }
    att = fabsf(att);

    float t0 = ftanh(ce.x), t1 = ftanh(ce.y), t2 = ftanh(ce.z), t3 = ftanh(ce.w);

    __syncthreads();

    float acc = 0.f;
    #pragma unroll 8
    for (int c = 0; c < H_; ++c) {
        float4 f0 = FS[2 * c];
        float4 f1 = FS[2 * c + 1];
        float h = ftanh(fmaf(t3, f0.w, fmaf(t2, f0.z,
                        fmaf(t1, f0.y, fmaf(t0, f0.x, f1.x)))));
        h = ftanh(fmaf(h, f1.y, f1.z));
        acc = fmaf(h, f1.w, acc);
    }
    float val = fmaxf(acc + b2[0], 0.f);

    // intra-wave dedup of duplicate cols, deterministic ascending-lane order
    float vsum = val, asum = att;
    bool leader = true;
    for (int j = 0; j < 64; ++j) {
        int   bc = __shfl(col, j);
        float bv = __shfl(val, j);
        float ba = __shfl(att, j);
        if (bc == col && j != lane) {
            if (j < lane) leader = false;
            else { vsum += bv; asum += ba; }
        }
    }
    if (leader) {
        size_t p = (size_t)row * N_ + col;
        out[p] = vsum * __expf(-asum * geo[p]) * ang[p];
    }
}

extern "C" void kernel_launch(void* const* d_in, const int* in_sizes, int n_in,
                              void* d_out, int out_size, void* d_ws, size_t ws_size,
                              hipStream_t stream)
{
    const float* coor  = (const float*)d_in[1];
    const int*   idx   = (const int*)d_in[2];
    const float* geo   = (const float*)d_in[3];
    const float* ang   = (const float*)d_in[4];
    const float* W0    = (const float*)d_in[5];
    const float* b0    = (const float*)d_in[6];
    const float* W1    = (const float*)d_in[7];
    const float* b1    = (const float*)d_in[8];
    const float* gamma = (const float*)d_in[9];
    const float* beta  = (const float*)d_in[10];
    const float* W2    = (const float*)d_in[11];
    const float* b2    = (const float*)d_in[12];
    const float* Wq    = (const float*)d_in[13];
    const float* bq    = (const float*)d_in[14];
    const float* Wk    = (const float*)d_in[15];
    const float* bk    = (const float*)d_in[16];

    float* ws = (float*)d_ws;
    float* sums   = ws;          // 512 f32
    float* W01    = ws + 512;    // 1024 f32
    float* b01    = ws + 1536;   // 256 f32
    float* folded = ws + 1792;   // 2048 f32

    const size_t NB = (size_t)N_ * N_ * sizeof(float);
    hipMemsetAsync(d_out, 0, NB, stream);                 // dense zeros
    hipMemsetAsync(ws, 0, 1792 * sizeof(float), stream);  // sums + W01 + b01

    prep_kernel<<<32, 256, 0, stream>>>(W0, b0, W1, b1, W01, b01);
    stats_kernel<<<E_ / 128, 256, 0, stream>>>(coor, W01, b01, sums);
    finalize_kernel<<<1, 256, 0, stream>>>(sums, gamma, beta, W2, W01, b01, folded);
    edge_kernel<<<N_ / 4, 256, 0, stream>>>(coor, idx, folded, Wq, bq, Wk, bk, b2,
                                            geo, ang, (float*)d_out);
}

// Round 4
// 79.721 us; speedup vs baseline: 1.5543x; 1.5543x over previous
//
#include <hip/hip_runtime.h>

#define N_ 4096
#define K_ 64
#define E_ (N_*K_)
#define H_ 256
#define EPS_ 1e-5f
#define L2E_ 1.4426950408889634f   // log2(e)
#define TL2E_ 2.8853900817779268f  // 2*log2(e)

#if __has_builtin(__builtin_amdgcn_exp2f)
#define EXP2(x) __builtin_amdgcn_exp2f(x)
#else
#define EXP2(x) __expf((x) * 0.6931471805599453f)
#endif

// tanh(x) = 1 - 2/(2^(2*log2e*x)+1); inf-safe (exp2(+inf)->inf, rcp(inf)=0)
__device__ __forceinline__ float ftanh(float x) {
    float e = EXP2(x * TL2E_);
    return 1.0f - 2.0f * __builtin_amdgcn_rcpf(e + 1.0f);
}

// W01 = W0 @ W1 (4x256), b01 = b0 @ W1 (+ b1). 32 blocks x 8 h-rows, atomic
// accumulate (32-deep chains, cheap). W01/b01 pre-zeroed by ws memset.
__global__ __launch_bounds__(256) void prep_kernel(
    const float* __restrict__ W0, const float* __restrict__ b0,
    const float* __restrict__ W1, const float* __restrict__ b1,
    float* __restrict__ W01, float* __restrict__ b01)
{
    int c = threadIdx.x;
    int h0 = blockIdx.x * 8;
    float a0 = 0.f, a1 = 0.f, a2 = 0.f, a3 = 0.f, ab = 0.f;
    #pragma unroll
    for (int h = h0; h < h0 + 8; ++h) {
        float w = W1[h * H_ + c];
        a0 = fmaf(W0[0 * H_ + h], w, a0);
        a1 = fmaf(W0[1 * H_ + h], w, a1);
        a2 = fmaf(W0[2 * H_ + h], w, a2);
        a3 = fmaf(W0[3 * H_ + h], w, a3);
        ab = fmaf(b0[h], w, ab);
    }
    if (blockIdx.x == 0) ab += b1[c];
    atomicAdd(&W01[c], a0);
    atomicAdd(&W01[H_ + c], a1);
    atomicAdd(&W01[2 * H_ + c], a2);
    atomicAdd(&W01[3 * H_ + c], a3);
    atomicAdd(&b01[c], ab);
}

// Per-column partial sums of r = 1/(2^(u'')+1) and r^2 over a 128-edge tile.
// (h = 1-2r; mean/var recovered from SR,SR2 in finalize.) NO atomics: each
// block writes its own 512-float row of `part`.
__global__ __launch_bounds__(256, 8) void stats_kernel(
    const float* __restrict__ coor, const float* __restrict__ W01,
    const float* __restrict__ b01, float* __restrict__ part)
{
    const int c = threadIdx.x;
    const float w0 = TL2E_ * W01[c],        w1 = TL2E_ * W01[H_ + c];
    const float w2 = TL2E_ * W01[2*H_ + c], w3 = TL2E_ * W01[3*H_ + c];
    const float bb = TL2E_ * b01[c];
    __shared__ float4 T[128];
    const int e0 = blockIdx.x * 128;
    if (c < 128) {
        float4 v = reinterpret_cast<const float4*>(coor)[e0 + c];
        T[c] = make_float4(ftanh(v.x), ftanh(v.y), ftanh(v.z), ftanh(v.w));
    }
    __syncthreads();
    float sr = 0.f, sr2 = 0.f;
    #pragma unroll 8
    for (int i = 0; i < 128; ++i) {
        float4 t = T[i];
        float u = fmaf(t.w, w3, fmaf(t.z, w2, fmaf(t.y, w1, fmaf(t.x, w0, bb))));
        float r = __builtin_amdgcn_rcpf(EXP2(u) + 1.0f);
        sr += r;
        sr2 = fmaf(r, r, sr2);
    }
    part[blockIdx.x * 512 + c] = sr;
    part[blockIdx.x * 512 + 256 + c] = sr2;
}

// Tree-reduce part[2048][512] -> sums[512]. 32 blocks x 64 rows each,
// then one atomic per column per block (32-deep chains).
__global__ __launch_bounds__(512) void reduce_kernel(
    const float* __restrict__ part, float* __restrict__ sums)
{
    int t = threadIdx.x;
    int b0 = blockIdx.x * 64;
    float local = 0.f;
    #pragma unroll 8
    for (int b = b0; b < b0 + 64; ++b) local += part[b * 512 + t];
    atomicAdd(&sums[t], local);
}

// Fold BN+weights into per-column record {w'',x4, bb'', A2, AB, -2*W2c},
// all exp2-prescaled; also SW = sum(W2)+b2.
__global__ __launch_bounds__(256) void finalize_kernel(
    const float* __restrict__ sums, const float* __restrict__ gamma,
    const float* __restrict__ beta, const float* __restrict__ W2,
    const float* __restrict__ b2,
    const float* __restrict__ W01, const float* __restrict__ b01,
    float* __restrict__ folded, float* __restrict__ swp)
{
    int c = threadIdx.x;
    const float inv = 1.0f / (float)E_;
    float p = sums[c] * inv;          // SR/E
    float q = sums[256 + c] * inv;    // SR2/E
    float mu = 1.0f - 2.0f * p;       // mean of h = 1-2r
    float var = 4.0f * fmaf(-p, p, q);
    float a = gamma[c] * rsqrtf(var + EPS_);
    float bf = fmaf(-mu, a, beta[c]);
    folded[c * 8 + 0] = TL2E_ * W01[c];
    folded[c * 8 + 1] = TL2E_ * W01[H_ + c];
    folded[c * 8 + 2] = TL2E_ * W01[2 * H_ + c];
    folded[c * 8 + 3] = TL2E_ * W01[3 * H_ + c];
    folded[c * 8 + 4] = TL2E_ * b01[c];
    folded[c * 8 + 5] = -4.0f * L2E_ * a;        // coeff of r
    folded[c * 8 + 6] = TL2E_ * (a + bf);        // const term
    folded[c * 8 + 7] = -2.0f * W2[c];           // acc coeff on r2
    __shared__ float red[256];
    red[c] = W2[c];
    __syncthreads();
    for (int s = 128; s > 0; s >>= 1) {
        if (c < s) red[c] += red[c + s];
        __syncthreads();
    }
    if (c == 0) swp[0] = red[0] + b2[0];
}

// Fused edge kernel. Block = 2 rows x 2 column-halves (4 waves). Each wave:
// 128 columns of the per-edge chain acc += (-2W2c)*r2. Halves combined via
// LDS; half-0 wave dedups duplicate cols (deterministic) and writes
// out[p] = vsum*exp(-asum*geo[p])*ang[p]. Block also zero-fills its 2 rows
// (replaces the 64MB memset; barrier's vmcnt drain orders zero vs final write).
__global__ __launch_bounds__(256, 8) void edge_kernel(
    const float* __restrict__ coor, const int* __restrict__ idx,
    const float* __restrict__ folded, const float* __restrict__ swp,
    const float* __restrict__ Wq, const float* __restrict__ bq,
    const float* __restrict__ Wk, const float* __restrict__ bk,
    const float* __restrict__ geo, const float* __restrict__ ang,
    float* __restrict__ out)
{
    __shared__ float4 FS[2 * H_];   // 8 KB folded table
    __shared__ float accbuf[4][64];
    const int t = threadIdx.x;
    {
        const float4* F = reinterpret_cast<const float4*>(folded);
        FS[t] = F[t];
        FS[t + 256] = F[t + 256];
    }
    const int w = t >> 6, lane = t & 63;
    const int rloc = w >> 1, half = w & 1;
    const int row = blockIdx.x * 2 + rloc;
    const int e = row * K_ + lane;

    // zero-fill this wave's half-row of out (1024 float4 per row total)
    {
        float4 z = make_float4(0.f, 0.f, 0.f, 0.f);
        float4* orow = reinterpret_cast<float4*>(out + (size_t)row * N_);
        #pragma unroll
        for (int i = 0; i < 8; ++i) orow[half * 512 + i * 64 + lane] = z;
    }

    const int col = idx[E_ + e];
    float4 ce = reinterpret_cast<const float4*>(coor)[e];
    float ex = ce.x + ce.z, ey = ce.y + ce.w;
    float sx = __shfl(ex, 0), sy = __shfl(ey, 0);   // row-center (lane 0)
    float att = 0.f;
    #pragma unroll
    for (int j = 0; j < 8; ++j) {
        float qj = fmaf(sy, Wq[8 + j], fmaf(sx, Wq[j], bq[j]));
        float kj = fmaf(ey, Wk[8 + j], fmaf(ex, Wk[j], bk[j]));
        att = fmaf(qj, kj, att);
    }
    att = fabsf(att);

    float t0 = ftanh(ce.x), t1 = ftanh(ce.y), t2 = ftanh(ce.z), t3 = ftanh(ce.w);

    __syncthreads();   // FS ready

    const float4* Fp = &FS[half * 256];
    float acc = 0.f;
    #pragma unroll 4
    for (int i = 0; i < 128; ++i) {
        float4 f0 = Fp[2 * i];
        float4 f1 = Fp[2 * i + 1];
        float u = fmaf(t3, f0.w, fmaf(t2, f0.z, fmaf(t1, f0.y, fmaf(t0, f0.x, f1.x))));
        float r  = __builtin_amdgcn_rcpf(EXP2(u) + 1.0f);
        float r2 = __builtin_amdgcn_rcpf(EXP2(fmaf(r, f1.y, f1.z)) + 1.0f);
        acc = fmaf(r2, f1.w, acc);
    }
    accbuf[w][lane] = acc;
    __syncthreads();   // also drains zero-fill stores (vmcnt before barrier)

    if (half == 0) {
        float val = fmaxf(accbuf[2 * rloc][lane] + accbuf[2 * rloc + 1][lane] + swp[0], 0.f);
        // intra-wave dedup of duplicate cols, deterministic ascending-lane order
        float vsum = val, asum = att;
        bool leader = true;
        for (int j = 0; j < 64; ++j) {
            int   bc = __shfl(col, j);
            float bv = __shfl(val, j);
            float ba = __shfl(att, j);
            if (bc == col && j != lane) {
                if (j < lane) leader = false;
                else { vsum += bv; asum += ba; }
            }
        }
        if (leader) {
            size_t p = (size_t)row * N_ + col;
            out[p] = vsum * __expf(-asum * geo[p]) * ang[p];
        }
    }
}

extern "C" void kernel_launch(void* const* d_in, const int* in_sizes, int n_in,
                              void* d_out, int out_size, void* d_ws, size_t ws_size,
                              hipStream_t stream)
{
    const float* coor  = (const float*)d_in[1];
    const int*   idx   = (const int*)d_in[2];
    const float* geo   = (const float*)d_in[3];
    const float* ang   = (const float*)d_in[4];
    const float* W0    = (const float*)d_in[5];
    const float* b0    = (const float*)d_in[6];
    const float* W1    = (const float*)d_in[7];
    const float* b1    = (const float*)d_in[8];
    const float* gamma = (const float*)d_in[9];
    const float* beta  = (const float*)d_in[10];
    const float* W2    = (const float*)d_in[11];
    const float* b2    = (const float*)d_in[12];
    const float* Wq    = (const float*)d_in[13];
    const float* bq    = (const float*)d_in[14];
    const float* Wk    = (const float*)d_in[15];
    const float* bk    = (const float*)d_in[16];

    float* ws = (float*)d_ws;
    float* sums   = ws;            // 512
    float* W01    = ws + 512;      // 1024
    float* b01    = ws + 1536;     // 256
    float* folded = ws + 1792;     // 2048
    float* swp    = ws + 3840;     // 1
    float* part   = ws + 4096;     // 2048*512 = 1M floats (4 MB)

    hipMemsetAsync(ws, 0, 1792 * sizeof(float), stream);  // sums + W01 + b01

    prep_kernel<<<32, 256, 0, stream>>>(W0, b0, W1, b1, W01, b01);
    stats_kernel<<<E_ / 128, 256, 0, stream>>>(coor, W01, b01, part);
    reduce_kernel<<<32, 512, 0, stream>>>(part, sums);
    finalize_kernel<<<1, 256, 0, stream>>>(sums, gamma, beta, W2, b2, W01, b01,
                                           folded, swp);
    edge_kernel<<<N_ / 2, 256, 0, stream>>>(coor, idx, folded, swp,
                                            Wq, bq, Wk, bk, geo, ang, (float*)d_out);
}

// Round 5
// 77.696 us; speedup vs baseline: 1.5948x; 1.0261x over previous
//
#include <hip/hip_runtime.h>

#define N_ 4096
#define K_ 64
#define E_ (N_*K_)
#define H_ 256
#define EPS_ 1e-5f
#define L2E_ 1.4426950408889634f   // log2(e)
#define TL2E_ 2.8853900817779268f  // 2*log2(e)

#if __has_builtin(__builtin_amdgcn_exp2f)
#define EXP2(x) __builtin_amdgcn_exp2f(x)
#else
#define EXP2(x) __expf((x) * 0.6931471805599453f)
#endif

// tanh(x) = 1 - 2/(2^(2*log2e*x)+1); inf-safe (exp2(+inf)->inf, rcp(inf)=0)
__device__ __forceinline__ float ftanh(float x) {
    float e = EXP2(x * TL2E_);
    return 1.0f - 2.0f * __builtin_amdgcn_rcpf(e + 1.0f);
}

// W01 = W0 @ W1 (4x256), b01 = b0 @ W1 (+ b1). 32 blocks x 8 h-rows, atomic
// accumulate (32-deep chains, cheap). W01/b01 pre-zeroed by ws memset.
__global__ __launch_bounds__(256) void prep_kernel(
    const float* __restrict__ W0, const float* __restrict__ b0,
    const float* __restrict__ W1, const float* __restrict__ b1,
    float* __restrict__ W01, float* __restrict__ b01)
{
    int c = threadIdx.x;
    int h0 = blockIdx.x * 8;
    float a0 = 0.f, a1 = 0.f, a2 = 0.f, a3 = 0.f, ab = 0.f;
    #pragma unroll
    for (int h = h0; h < h0 + 8; ++h) {
        float w = W1[h * H_ + c];
        a0 = fmaf(W0[0 * H_ + h], w, a0);
        a1 = fmaf(W0[1 * H_ + h], w, a1);
        a2 = fmaf(W0[2 * H_ + h], w, a2);
        a3 = fmaf(W0[3 * H_ + h], w, a3);
        ab = fmaf(b0[h], w, ab);
    }
    if (blockIdx.x == 0) ab += b1[c];
    atomicAdd(&W01[c], a0);
    atomicAdd(&W01[H_ + c], a1);
    atomicAdd(&W01[2 * H_ + c], a2);
    atomicAdd(&W01[3 * H_ + c], a3);
    atomicAdd(&b01[c], ab);
}

// Per-column partial sums of r = 1/(2^(u'')+1) and r^2 over a 128-edge tile.
// NO atomics: each block writes its own 512-float row of `part`.
__global__ __launch_bounds__(256, 8) void stats_kernel(
    const float* __restrict__ coor, const float* __restrict__ W01,
    const float* __restrict__ b01, float* __restrict__ part)
{
    const int c = threadIdx.x;
    const float w0 = TL2E_ * W01[c],        w1 = TL2E_ * W01[H_ + c];
    const float w2 = TL2E_ * W01[2*H_ + c], w3 = TL2E_ * W01[3*H_ + c];
    const float bb = TL2E_ * b01[c];
    __shared__ float4 T[128];
    const int e0 = blockIdx.x * 128;
    if (c < 128) {
        float4 v = reinterpret_cast<const float4*>(coor)[e0 + c];
        T[c] = make_float4(ftanh(v.x), ftanh(v.y), ftanh(v.z), ftanh(v.w));
    }
    __syncthreads();
    float sr = 0.f, sr2 = 0.f;
    #pragma unroll 8
    for (int i = 0; i < 128; ++i) {
        float4 t = T[i];
        float u = fmaf(t.w, w3, fmaf(t.z, w2, fmaf(t.y, w1, fmaf(t.x, w0, bb))));
        float r = __builtin_amdgcn_rcpf(EXP2(u) + 1.0f);
        sr += r;
        sr2 = fmaf(r, r, sr2);
    }
    part[blockIdx.x * 512 + c] = sr;
    part[blockIdx.x * 512 + 256 + c] = sr2;
}

// Tree-reduce part[2048][512] -> sums[512]. 32 blocks x 64 rows each.
__global__ __launch_bounds__(512) void reduce_kernel(
    const float* __restrict__ part, float* __restrict__ sums)
{
    int t = threadIdx.x;
    int b0 = blockIdx.x * 64;
    float local = 0.f;
    #pragma unroll 8
    for (int b = b0; b < b0 + 64; ++b) local += part[b * 512 + t];
    atomicAdd(&sums[t], local);
}

// Fold BN+weights into per-column record, exp2-prescaled; SW = sum(W2)+b2.
__global__ __launch_bounds__(256) void finalize_kernel(
    const float* __restrict__ sums, const float* __restrict__ gamma,
    const float* __restrict__ beta, const float* __restrict__ W2,
    const float* __restrict__ b2,
    const float* __restrict__ W01, const float* __restrict__ b01,
    float* __restrict__ folded, float* __restrict__ swp)
{
    int c = threadIdx.x;
    const float inv = 1.0f / (float)E_;
    float p = sums[c] * inv;          // SR/E
    float q = sums[256 + c] * inv;    // SR2/E
    float mu = 1.0f - 2.0f * p;       // mean of h = 1-2r
    float var = 4.0f * fmaf(-p, p, q);
    float a = gamma[c] * rsqrtf(var + EPS_);
    float bf = fmaf(-mu, a, beta[c]);
    folded[c * 8 + 0] = TL2E_ * W01[c];
    folded[c * 8 + 1] = TL2E_ * W01[H_ + c];
    folded[c * 8 + 2] = TL2E_ * W01[2 * H_ + c];
    folded[c * 8 + 3] = TL2E_ * W01[3 * H_ + c];
    folded[c * 8 + 4] = TL2E_ * b01[c];
    folded[c * 8 + 5] = -4.0f * L2E_ * a;        // coeff of r
    folded[c * 8 + 6] = TL2E_ * (a + bf);        // const term
    folded[c * 8 + 7] = -2.0f * W2[c];           // acc coeff on r2
    __shared__ float red[256];
    red[c] = W2[c];
    __syncthreads();
    for (int s = 128; s > 0; s >>= 1) {
        if (c < s) red[c] += red[c + s];
        __syncthreads();
    }
    if (c == 0) swp[0] = red[0] + b2[0];
}

// Fused edge kernel, block = 2 rows (128 edges).
// Phase 0: stage folded table (8KB), per-edge tanh quads + (ex,ey); zero-fill
//          the block's 2 output rows (replaces 64MB memset).
// Phase 1: thread = 4 edges x 32 columns -> weights f0,f1 loaded once serve
//          4 evals (ds reads/eval 2 -> 0.5). Partials to ACC[8][128].
// Phase 2: waves 0,1 = rows; sum 8 chunk-partials, attention, deterministic
//          intra-wave dedup, out[p] = vsum*exp(-asum*geo[p])*ang[p].
__global__ __launch_bounds__(256, 8) void edge_kernel(
    const float* __restrict__ coor, const int* __restrict__ idx,
    const float* __restrict__ folded, const float* __restrict__ swp,
    const float* __restrict__ Wq, const float* __restrict__ bq,
    const float* __restrict__ Wk, const float* __restrict__ bk,
    const float* __restrict__ geo, const float* __restrict__ ang,
    float* __restrict__ out)
{
    __shared__ float4 FS[2 * H_];   // folded: col c -> FS[2c], FS[2c+1]
    __shared__ float4 TS[128];      // per-edge tanh quads
    __shared__ float2 EXY[128];     // per-edge (ex,ey)
    __shared__ float  ACC[8][128];  // chunk x edge partial accs

    const int t = threadIdx.x;
    const int row0 = blockIdx.x * 2;
    {
        const float4* F = reinterpret_cast<const float4*>(folded);
        FS[t] = F[t];
        FS[t + 256] = F[t + 256];
    }
    if (t < 128) {
        float4 ce = reinterpret_cast<const float4*>(coor)[row0 * K_ + t];
        TS[t] = make_float4(ftanh(ce.x), ftanh(ce.y), ftanh(ce.z), ftanh(ce.w));
        EXY[t] = make_float2(ce.x + ce.z, ce.y + ce.w);
    }
    {   // zero-fill this block's 2 rows: 2048 float4, 8 per thread, coalesced
        float4 z = make_float4(0.f, 0.f, 0.f, 0.f);
        float4* orow = reinterpret_cast<float4*>(out + (size_t)row0 * N_);
        #pragma unroll
        for (int i = 0; i < 8; ++i) orow[i * 256 + t] = z;
    }
    __syncthreads();   // TS/FS ready; zero stores drained (vmcnt before barrier)

    // ---- compute: 4 edges x 32 columns per thread ----
    const int eg = (t & 31) * 4;      // first of 4 edges
    const int chunk = t >> 5;         // column chunk (0..7)
    const float4 tq0 = TS[eg], tq1 = TS[eg + 1], tq2 = TS[eg + 2], tq3 = TS[eg + 3];
    const float4* Fp = &FS[chunk * 64];
    float a0 = 0.f, a1 = 0.f, a2 = 0.f, a3 = 0.f;
    #pragma unroll 4
    for (int i = 0; i < 32; ++i) {
        float4 f0 = Fp[2 * i];
        float4 f1 = Fp[2 * i + 1];
        #define EVAL(tq, ak) { \
            float u = fmaf(tq.w, f0.w, fmaf(tq.z, f0.z, fmaf(tq.y, f0.y, fmaf(tq.x, f0.x, f1.x)))); \
            float r = __builtin_amdgcn_rcpf(EXP2(u) + 1.0f); \
            float r2 = __builtin_amdgcn_rcpf(EXP2(fmaf(r, f1.y, f1.z)) + 1.0f); \
            ak = fmaf(r2, f1.w, ak); }
        EVAL(tq0, a0) EVAL(tq1, a1) EVAL(tq2, a2) EVAL(tq3, a3)
        #undef EVAL
    }
    *reinterpret_cast<float4*>(&ACC[chunk][eg]) = make_float4(a0, a1, a2, a3);
    __syncthreads();

    // ---- write phase: waves 0,1 -> rows row0, row0+1 ----
    const int w = t >> 6, lane = t & 63;
    if (w < 2) {
        const int row = row0 + w;
        const int eb = w * 64 + lane;
        float val = swp[0];
        #pragma unroll
        for (int c = 0; c < 8; ++c) val += ACC[c][eb];
        val = fmaxf(val, 0.f);

        float2 exy = EXY[eb];
        float ex = exy.x, ey = exy.y;
        float sx = __shfl(ex, 0), sy = __shfl(ey, 0);   // row center = lane 0
        float att = 0.f;
        #pragma unroll
        for (int j = 0; j < 8; ++j) {
            float qj = fmaf(sy, Wq[8 + j], fmaf(sx, Wq[j], bq[j]));
            float kj = fmaf(ey, Wk[8 + j], fmaf(ex, Wk[j], bk[j]));
            att = fmaf(qj, kj, att);
        }
        att = fabsf(att);

        const int col = idx[E_ + row * K_ + lane];
        float vsum = val, asum = att;
        bool leader = true;
        for (int j = 0; j < 64; ++j) {
            int   bc = __shfl(col, j);
            float bv = __shfl(val, j);
            float ba = __shfl(att, j);
            if (bc == col && j != lane) {
                if (j < lane) leader = false;
                else { vsum += bv; asum += ba; }
            }
        }
        if (leader) {
            size_t p = (size_t)row * N_ + col;
            out[p] = vsum * __expf(-asum * geo[p]) * ang[p];
        }
    }
}

extern "C" void kernel_launch(void* const* d_in, const int* in_sizes, int n_in,
                              void* d_out, int out_size, void* d_ws, size_t ws_size,
                              hipStream_t stream)
{
    const float* coor  = (const float*)d_in[1];
    const int*   idx   = (const int*)d_in[2];
    const float* geo   = (const float*)d_in[3];
    const float* ang   = (const float*)d_in[4];
    const float* W0    = (const float*)d_in[5];
    const float* b0    = (const float*)d_in[6];
    const float* W1    = (const float*)d_in[7];
    const float* b1    = (const float*)d_in[8];
    const float* gamma = (const float*)d_in[9];
    const float* beta  = (const float*)d_in[10];
    const float* W2    = (const float*)d_in[11];
    const float* b2    = (const float*)d_in[12];
    const float* Wq    = (const float*)d_in[13];
    const float* bq    = (const float*)d_in[14];
    const float* Wk    = (const float*)d_in[15];
    const float* bk    = (const float*)d_in[16];

    float* ws = (float*)d_ws;
    float* sums   = ws;            // 512
    float* W01    = ws + 512;      // 1024
    float* b01    = ws + 1536;     // 256
    float* folded = ws + 1792;     // 2048
    float* swp    = ws + 3840;     // 1
    float* part   = ws + 4096;     // 2048*512 floats (4 MB)

    hipMemsetAsync(ws, 0, 1792 * sizeof(float), stream);  // sums + W01 + b01

    prep_kernel<<<32, 256, 0, stream>>>(W0, b0, W1, b1, W01, b01);
    stats_kernel<<<E_ / 128, 256, 0, stream>>>(coor, W01, b01, part);
    reduce_kernel<<<32, 512, 0, stream>>>(part, sums);
    finalize_kernel<<<1, 256, 0, stream>>>(sums, gamma, beta, W2, b2, W01, b01,
                                           folded, swp);
    edge_kernel<<<N_ / 2, 256, 0, stream>>>(coor, idx, folded, swp,
                                            Wq, bq, Wk, bk, geo, ang, (float*)d_out);
}